// Round 3
// baseline (751.525 us; speedup 1.0000x reference)
//
#include <hip/hip_runtime.h>

// GCNPredictor: 3-layer GCN (sum-aggregation) + sum-pool + MLP head, fp32.
// Round 3: edge-parallel gather (contiguous CSR slice per block) with LDS
// atomic accumulation -> 32 concurrent row-streams per block (was 2).

constexpr int NUM_GRAPHS = 2048;

// ---------------- h0 = x @ W_emb  ([N,35] @ [35,8]) ----------------
__global__ __launch_bounds__(256) void k_embed(const float* __restrict__ x,
                                               const float* __restrict__ Wemb,
                                               float* __restrict__ h0, int N) {
  __shared__ float sx[32 * 35];
  __shared__ float sw[35 * 8];
  int n0 = blockIdx.x * 32;
  int cnt = min(32, N - n0);
  int nf = cnt * 35;
  for (int i = threadIdx.x; i < nf; i += 256) sx[i] = x[(size_t)n0 * 35 + i];
  for (int i = threadIdx.x; i < 35 * 8; i += 256) sw[i] = Wemb[i];
  __syncthreads();
  int nl = threadIdx.x >> 3;
  int c = threadIdx.x & 7;
  if (nl < cnt) {
    float acc = 0.f;
#pragma unroll
    for (int k = 0; k < 35; ++k) acc = fmaf(sx[nl * 35 + k], sw[k * 8 + c], acc);
    h0[(size_t)(n0 + nl) * 8 + c] = acc;
  }
}

// ---------------- CSR build: counts -> exclusive scan -> fill ----------------
__global__ __launch_bounds__(256) void k_hist(const int* __restrict__ dst,
                                              int* counts, int E) {
  int e = blockIdx.x * 256 + threadIdx.x;
  if (e < E) atomicAdd(&counts[dst[e]], 1);
}

__global__ __launch_bounds__(256) void k_scan1(const int* __restrict__ counts,
                                               int* __restrict__ offs,
                                               int* __restrict__ partials, int N) {
  __shared__ int s[256];
  int i = blockIdx.x * 256 + threadIdx.x;
  int v = (i < N) ? counts[i] : 0;
  s[threadIdx.x] = v;
  __syncthreads();
#pragma unroll
  for (int d = 1; d < 256; d <<= 1) {
    int t = (threadIdx.x >= d) ? s[threadIdx.x - d] : 0;
    __syncthreads();
    s[threadIdx.x] += t;
    __syncthreads();
  }
  if (i < N) offs[i] = s[threadIdx.x] - v;  // exclusive
  if (threadIdx.x == 255) partials[blockIdx.x] = s[255];
}

__global__ __launch_bounds__(512) void k_scan2(int* partials, int nb) {
  __shared__ int s[512];
  int t = threadIdx.x;
  int orig = (t < nb) ? partials[t] : 0;
  s[t] = orig;
  __syncthreads();
#pragma unroll
  for (int d = 1; d < 512; d <<= 1) {
    int v = (t >= d) ? s[t - d] : 0;
    __syncthreads();
    s[t] += v;
    __syncthreads();
  }
  if (t < nb) partials[t] = s[t] - orig;  // exclusive block offsets
}

__global__ __launch_bounds__(256) void k_scan3(int* __restrict__ offs,
                                               const int* __restrict__ partials,
                                               int* __restrict__ cursor, int N) {
  int i = blockIdx.x * 256 + threadIdx.x;
  if (i < N) {
    int v = offs[i] + partials[blockIdx.x];
    offs[i] = v;
    cursor[i] = v;
  }
}

__global__ __launch_bounds__(256) void k_fill(const int* __restrict__ src,
                                              const int* __restrict__ dst,
                                              int* cursor, int2* __restrict__ csr2,
                                              int E) {
  int e = blockIdx.x * 256 + threadIdx.x;
  if (e < E) {
    int d = dst[e];
    int slot = atomicAdd(&cursor[d], 1);
    csr2[slot] = make_int2(src[e], d);
  }
}

// -------- layer 0 fused: agg8 = gather(h0); out = relu(agg8 @ W_g0) --------
__global__ __launch_bounds__(256) void k_layer0(const float* __restrict__ h0,
                                                const int2* __restrict__ csr2,
                                                const int* __restrict__ offs,
                                                const int* __restrict__ cnts,
                                                const float* __restrict__ W,
                                                float* __restrict__ out, int N) {
  __shared__ float sagg[32 * 9];  // stride 9: conflict-free
  __shared__ float sw[8 * 128];
  for (int i = threadIdx.x; i < 1024; i += 256) sw[i] = W[i];
  int n0 = blockIdx.x * 32;
  {
    int i = threadIdx.x >> 3;
    int c = threadIdx.x & 7;
    int n = n0 + i;
    float acc = 0.f;
    if (n < N) {
      int s = offs[n], cc = cnts[n];
      for (int e = 0; e < cc; ++e) acc += h0[(size_t)csr2[s + e].x * 8 + c];
    }
    sagg[i * 9 + c] = acc;
  }
  __syncthreads();
  int i2 = threadIdx.x >> 3;
  int j0 = (threadIdx.x & 7) * 16;
  int n2 = n0 + i2;
  if (n2 >= N) return;
  float a[8];
#pragma unroll
  for (int k = 0; k < 8; ++k) a[k] = sagg[i2 * 9 + k];
  float o[16];
#pragma unroll
  for (int j = 0; j < 16; ++j) o[j] = 0.f;
#pragma unroll
  for (int k = 0; k < 8; ++k)
#pragma unroll
    for (int j = 0; j < 16; ++j) o[j] = fmaf(a[k], sw[k * 128 + j0 + j], o[j]);
  size_t base = (size_t)n2 * 128 + j0;
#pragma unroll
  for (int t = 0; t < 4; ++t) {
    float4 v;
    v.x = fmaxf(o[t * 4 + 0], 0.f);
    v.y = fmaxf(o[t * 4 + 1], 0.f);
    v.z = fmaxf(o[t * 4 + 2], 0.f);
    v.w = fmaxf(o[t * 4 + 3], 0.f);
    *reinterpret_cast<float4*>(&out[base + t * 4]) = v;
  }
}

// -------- fused GCN layer (d=128): agg = gather(H); v = relu(agg@W) + H --------
// Gather is edge-parallel over the block's contiguous CSR slice, accumulating
// with LDS atomics. mode 0: out[n] = v. mode 1: G[gid[n]] += v (pool fused).
__global__ __launch_bounds__(256) void k_gcn_fused(
    const float* __restrict__ H, const int2* __restrict__ csr2,
    const int* __restrict__ offs,
    const float* __restrict__ W, float* __restrict__ out,
    float* G, const int* __restrict__ gid, int N, int E, int mode) {
  __shared__ float sa[64 * 132];
  int n0 = blockIdx.x * 64;

  // zero the tile
  for (int i = threadIdx.x; i < 64 * 132; i += 256) sa[i] = 0.f;
  __syncthreads();

  // edge-parallel gather: 8 groups x 32 lanes, float4 per lane, unroll x4
  {
    int e0 = offs[n0];
    int e1 = (n0 + 64 < N) ? offs[n0 + 64] : E;
    int grp = threadIdx.x >> 5;
    int lane = threadIdx.x & 31;
    int c4 = lane * 4;
    int e = e0 + grp;
    for (; e + 24 < e1; e += 32) {
      int2 p0 = csr2[e];
      int2 p1 = csr2[e + 8];
      int2 p2 = csr2[e + 16];
      int2 p3 = csr2[e + 24];
      float4 v0 = *reinterpret_cast<const float4*>(&H[(size_t)p0.x * 128 + c4]);
      float4 v1 = *reinterpret_cast<const float4*>(&H[(size_t)p1.x * 128 + c4]);
      float4 v2 = *reinterpret_cast<const float4*>(&H[(size_t)p2.x * 128 + c4]);
      float4 v3 = *reinterpret_cast<const float4*>(&H[(size_t)p3.x * 128 + c4]);
      float* d0 = &sa[(p0.y - n0) * 132 + c4];
      float* d1 = &sa[(p1.y - n0) * 132 + c4];
      float* d2 = &sa[(p2.y - n0) * 132 + c4];
      float* d3 = &sa[(p3.y - n0) * 132 + c4];
      atomicAdd(d0 + 0, v0.x); atomicAdd(d0 + 1, v0.y);
      atomicAdd(d0 + 2, v0.z); atomicAdd(d0 + 3, v0.w);
      atomicAdd(d1 + 0, v1.x); atomicAdd(d1 + 1, v1.y);
      atomicAdd(d1 + 2, v1.z); atomicAdd(d1 + 3, v1.w);
      atomicAdd(d2 + 0, v2.x); atomicAdd(d2 + 1, v2.y);
      atomicAdd(d2 + 2, v2.z); atomicAdd(d2 + 3, v2.w);
      atomicAdd(d3 + 0, v3.x); atomicAdd(d3 + 1, v3.y);
      atomicAdd(d3 + 2, v3.z); atomicAdd(d3 + 3, v3.w);
    }
    for (; e < e1; e += 8) {
      int2 p = csr2[e];
      float4 v = *reinterpret_cast<const float4*>(&H[(size_t)p.x * 128 + c4]);
      float* d = &sa[(p.y - n0) * 132 + c4];
      atomicAdd(d + 0, v.x); atomicAdd(d + 1, v.y);
      atomicAdd(d + 2, v.z); atomicAdd(d + 3, v.w);
    }
  }
  __syncthreads();

  // GEMM 64x128 @ 128x128
  int nl = threadIdx.x >> 4;
  int j0 = (threadIdx.x & 15) * 8;
  float acc[4][8];
#pragma unroll
  for (int r = 0; r < 4; ++r)
#pragma unroll
    for (int j = 0; j < 8; ++j) acc[r][j] = 0.f;
  const float* Wj = W + j0;
#pragma unroll 2
  for (int k = 0; k < 128; ++k) {
    float4 w0 = *reinterpret_cast<const float4*>(Wj + (size_t)k * 128);
    float4 w1 = *reinterpret_cast<const float4*>(Wj + (size_t)k * 128 + 4);
    float wv[8] = {w0.x, w0.y, w0.z, w0.w, w1.x, w1.y, w1.z, w1.w};
#pragma unroll
    for (int r = 0; r < 4; ++r) {
      float a = sa[(nl + 16 * r) * 132 + k];
#pragma unroll
      for (int j = 0; j < 8; ++j) acc[r][j] = fmaf(a, wv[j], acc[r][j]);
    }
  }

  if (mode == 0) {
#pragma unroll
    for (int r = 0; r < 4; ++r) {
      int row = nl + 16 * r;
      int n = n0 + row;
      if (n < N) {
        size_t base = (size_t)n * 128 + j0;
        float4 r0 = *reinterpret_cast<const float4*>(&H[base]);
        float4 r1 = *reinterpret_cast<const float4*>(&H[base + 4]);
        float4 o0, o1;
        o0.x = fmaxf(acc[r][0], 0.f) + r0.x;
        o0.y = fmaxf(acc[r][1], 0.f) + r0.y;
        o0.z = fmaxf(acc[r][2], 0.f) + r0.z;
        o0.w = fmaxf(acc[r][3], 0.f) + r0.w;
        o1.x = fmaxf(acc[r][4], 0.f) + r1.x;
        o1.y = fmaxf(acc[r][5], 0.f) + r1.y;
        o1.z = fmaxf(acc[r][6], 0.f) + r1.z;
        o1.w = fmaxf(acc[r][7], 0.f) + r1.w;
        *reinterpret_cast<float4*>(&out[base]) = o0;
        *reinterpret_cast<float4*>(&out[base + 4]) = o1;
      }
    }
  } else {
    __syncthreads();  // all GEMM reads of sa done
#pragma unroll
    for (int r = 0; r < 4; ++r) {
      int row = nl + 16 * r;
      int n = n0 + row;
      if (n < N) {
        size_t base = (size_t)n * 128 + j0;
        float4 r0 = *reinterpret_cast<const float4*>(&H[base]);
        float4 r1 = *reinterpret_cast<const float4*>(&H[base + 4]);
        float* srow = &sa[row * 132 + j0];
        srow[0] = fmaxf(acc[r][0], 0.f) + r0.x;
        srow[1] = fmaxf(acc[r][1], 0.f) + r0.y;
        srow[2] = fmaxf(acc[r][2], 0.f) + r0.z;
        srow[3] = fmaxf(acc[r][3], 0.f) + r0.w;
        srow[4] = fmaxf(acc[r][4], 0.f) + r1.x;
        srow[5] = fmaxf(acc[r][5], 0.f) + r1.y;
        srow[6] = fmaxf(acc[r][6], 0.f) + r1.z;
        srow[7] = fmaxf(acc[r][7], 0.f) + r1.w;
      }
    }
    __syncthreads();
    int grp = threadIdx.x >> 7;  // 0..1 -> rows [0,32) / [32,64)
    int j = threadIdx.x & 127;
    int r0 = grp * 32;
    int nfirst = n0 + r0;
    if (nfirst < N) {
      float pacc = 0.f;
      int cur = gid[nfirst];
      for (int r = r0; r < r0 + 32; ++r) {
        int n = n0 + r;
        if (n >= N) break;
        int g2 = gid[n];
        if (g2 != cur) {
          atomicAdd(&G[(size_t)cur * 128 + j], pacc);
          pacc = 0.f;
          cur = g2;
        }
        pacc += sa[r * 132 + j];
      }
      atomicAdd(&G[(size_t)cur * 128 + j], pacc);
    }
  }
}

// ---------------- pred = relu(g @ W_p1) @ W_p2 + b ----------------
__global__ __launch_bounds__(64) void k_head(const float* __restrict__ g,
                                             const float* __restrict__ W1,
                                             const float* __restrict__ W2,
                                             const float* __restrict__ b,
                                             float* __restrict__ out) {
  int gi = blockIdx.x;
  int j = threadIdx.x;
  __shared__ float sg[128];
  sg[j] = g[(size_t)gi * 128 + j];
  sg[j + 64] = g[(size_t)gi * 128 + 64 + j];
  __syncthreads();
  float acc = 0.f;
#pragma unroll
  for (int k = 0; k < 128; ++k) acc = fmaf(sg[k], W1[k * 64 + j], acc);
  acc = fmaxf(acc, 0.f) * W2[j];
#pragma unroll
  for (int off = 32; off > 0; off >>= 1) acc += __shfl_down(acc, off);
  if (j == 0) out[gi] = acc + b[0];
}

extern "C" void kernel_launch(void* const* d_in, const int* in_sizes, int n_in,
                              void* d_out, int out_size, void* d_ws, size_t ws_size,
                              hipStream_t stream) {
  const float* x    = (const float*)d_in[0];
  const float* Wemb = (const float*)d_in[1];
  const float* Wg0  = (const float*)d_in[2];
  const float* Wg1  = (const float*)d_in[3];
  const float* Wg2  = (const float*)d_in[4];
  const float* Wp1  = (const float*)d_in[5];
  const float* Wp2  = (const float*)d_in[6];
  const float* bp2  = (const float*)d_in[7];
  const int* esrc   = (const int*)d_in[8];
  const int* edst   = (const int*)d_in[9];
  const int* gids   = (const int*)d_in[10];
  int N = in_sizes[0] / 35;
  int E = in_sizes[8];
  float* out = (float*)d_out;

  // workspace layout
  float* h0 = (float*)d_ws;             // N*8
  float* P  = h0 + (size_t)N * 8;       // N*128
  float* Q  = P + (size_t)N * 128;      // N*128
  float* G  = Q + (size_t)N * 128;      // 2048*128
  int* counts   = (int*)(G + (size_t)NUM_GRAPHS * 128);  // N
  int* offs     = counts + N;                            // N
  int* cursor   = offs + N;                              // N
  int* partials = cursor + N;                            // 512
  int2* csr2    = (int2*)(partials + 512);               // E int2

  int nbE = (E + 255) / 256;
  int nbN = (N + 255) / 256;

  // embed (independent)
  k_embed<<<(N + 31) / 32, 256, 0, stream>>>(x, Wemb, h0, N);

  // CSR build
  hipMemsetAsync(counts, 0, (size_t)N * sizeof(int), stream);
  k_hist<<<nbE, 256, 0, stream>>>(edst, counts, E);
  k_scan1<<<nbN, 256, 0, stream>>>(counts, offs, partials, N);
  k_scan2<<<1, 512, 0, stream>>>(partials, nbN);
  k_scan3<<<nbN, 256, 0, stream>>>(offs, partials, cursor, N);
  k_fill<<<nbE, 256, 0, stream>>>(esrc, edst, cursor, csr2, E);

  // zero pooled output (layer-2 epilogue atomics accumulate into it)
  hipMemsetAsync(G, 0, (size_t)NUM_GRAPHS * 128 * sizeof(float), stream);

  // layer 0: P = relu(gather(h0) @ W_g0)
  k_layer0<<<(N + 31) / 32, 256, 0, stream>>>(h0, csr2, offs, counts, Wg0, P, N);

  // layer 1: Q = relu(gather(P) @ W_g1) + P
  k_gcn_fused<<<(N + 63) / 64, 256, 0, stream>>>(P, csr2, offs, Wg1, Q,
                                                 nullptr, nullptr, N, E, 0);

  // layer 2 + pool: G[gid] += relu(gather(Q) @ W_g2) + Q
  k_gcn_fused<<<(N + 63) / 64, 256, 0, stream>>>(Q, csr2, offs, Wg2, nullptr,
                                                 G, gids, N, E, 1);

  // head
  k_head<<<NUM_GRAPHS, 64, 0, stream>>>(G, Wp1, Wp2, bp2, out);
}

// Round 4
// 306.777 us; speedup vs baseline: 2.4497x; 2.4497x over previous
//
#include <hip/hip_runtime.h>

// GCNPredictor: 3-layer GCN (sum-aggregation) + sum-pool + MLP head, fp32.
// Round 4: node-per-lane, column-slice-per-wave gather. Each lane accumulates
// its node's 32-col slice in VGPRs via 8 independent dwordx4 loads per edge
// (no atomics, no LDS in the gather loop) -> one wave gather instruction keeps
// 64 scattered rows in flight; 16 waves/CU.

constexpr int NUM_GRAPHS = 2048;

// ---------------- h0 = x @ W_emb  ([N,35] @ [35,8]) ----------------
__global__ __launch_bounds__(256) void k_embed(const float* __restrict__ x,
                                               const float* __restrict__ Wemb,
                                               float* __restrict__ h0, int N) {
  __shared__ float sx[32 * 35];
  __shared__ float sw[35 * 8];
  int n0 = blockIdx.x * 32;
  int cnt = min(32, N - n0);
  int nf = cnt * 35;
  for (int i = threadIdx.x; i < nf; i += 256) sx[i] = x[(size_t)n0 * 35 + i];
  for (int i = threadIdx.x; i < 35 * 8; i += 256) sw[i] = Wemb[i];
  __syncthreads();
  int nl = threadIdx.x >> 3;
  int c = threadIdx.x & 7;
  if (nl < cnt) {
    float acc = 0.f;
#pragma unroll
    for (int k = 0; k < 35; ++k) acc = fmaf(sx[nl * 35 + k], sw[k * 8 + c], acc);
    h0[(size_t)(n0 + nl) * 8 + c] = acc;
  }
}

// ---------------- CSR build: counts -> exclusive scan -> fill ----------------
__global__ __launch_bounds__(256) void k_hist(const int* __restrict__ dst,
                                              int* counts, int E) {
  int e = blockIdx.x * 256 + threadIdx.x;
  if (e < E) atomicAdd(&counts[dst[e]], 1);
}

__global__ __launch_bounds__(256) void k_scan1(const int* __restrict__ counts,
                                               int* __restrict__ offs,
                                               int* __restrict__ partials, int N) {
  __shared__ int s[256];
  int i = blockIdx.x * 256 + threadIdx.x;
  int v = (i < N) ? counts[i] : 0;
  s[threadIdx.x] = v;
  __syncthreads();
#pragma unroll
  for (int d = 1; d < 256; d <<= 1) {
    int t = (threadIdx.x >= d) ? s[threadIdx.x - d] : 0;
    __syncthreads();
    s[threadIdx.x] += t;
    __syncthreads();
  }
  if (i < N) offs[i] = s[threadIdx.x] - v;  // exclusive
  if (threadIdx.x == 255) partials[blockIdx.x] = s[255];
}

__global__ __launch_bounds__(512) void k_scan2(int* partials, int nb) {
  __shared__ int s[512];
  int t = threadIdx.x;
  int orig = (t < nb) ? partials[t] : 0;
  s[t] = orig;
  __syncthreads();
#pragma unroll
  for (int d = 1; d < 512; d <<= 1) {
    int v = (t >= d) ? s[t - d] : 0;
    __syncthreads();
    s[t] += v;
    __syncthreads();
  }
  if (t < nb) partials[t] = s[t] - orig;  // exclusive block offsets
}

__global__ __launch_bounds__(256) void k_scan3(int* __restrict__ offs,
                                               const int* __restrict__ partials,
                                               int* __restrict__ cursor, int N) {
  int i = blockIdx.x * 256 + threadIdx.x;
  if (i < N) {
    int v = offs[i] + partials[blockIdx.x];
    offs[i] = v;
    cursor[i] = v;
  }
}

__global__ __launch_bounds__(256) void k_fill(const int* __restrict__ src,
                                              const int* __restrict__ dst,
                                              int* cursor, int* __restrict__ csr,
                                              int E) {
  int e = blockIdx.x * 256 + threadIdx.x;
  if (e < E) {
    int slot = atomicAdd(&cursor[dst[e]], 1);
    csr[slot] = src[e];
  }
}

// -------- layer 0 fused: agg8 = gather(h0); out = relu(agg8 @ W_g0) --------
__global__ __launch_bounds__(256) void k_layer0(const float* __restrict__ h0,
                                                const int* __restrict__ csr,
                                                const int* __restrict__ offs,
                                                const int* __restrict__ cnts,
                                                const float* __restrict__ W,
                                                float* __restrict__ out, int N) {
  __shared__ float sagg[32 * 9];  // stride 9: conflict-free
  __shared__ float sw[8 * 128];
  for (int i = threadIdx.x; i < 1024; i += 256) sw[i] = W[i];
  int n0 = blockIdx.x * 32;
  {
    int i = threadIdx.x >> 3;
    int c = threadIdx.x & 7;
    int n = n0 + i;
    float acc = 0.f;
    if (n < N) {
      int s = offs[n], cc = cnts[n];
      for (int e = 0; e < cc; ++e) acc += h0[(size_t)csr[s + e] * 8 + c];
    }
    sagg[i * 9 + c] = acc;
  }
  __syncthreads();
  int i2 = threadIdx.x >> 3;
  int j0 = (threadIdx.x & 7) * 16;
  int n2 = n0 + i2;
  if (n2 >= N) return;
  float a[8];
#pragma unroll
  for (int k = 0; k < 8; ++k) a[k] = sagg[i2 * 9 + k];
  float o[16];
#pragma unroll
  for (int j = 0; j < 16; ++j) o[j] = 0.f;
#pragma unroll
  for (int k = 0; k < 8; ++k)
#pragma unroll
    for (int j = 0; j < 16; ++j) o[j] = fmaf(a[k], sw[k * 128 + j0 + j], o[j]);
  size_t base = (size_t)n2 * 128 + j0;
#pragma unroll
  for (int t = 0; t < 4; ++t) {
    float4 v;
    v.x = fmaxf(o[t * 4 + 0], 0.f);
    v.y = fmaxf(o[t * 4 + 1], 0.f);
    v.z = fmaxf(o[t * 4 + 2], 0.f);
    v.w = fmaxf(o[t * 4 + 3], 0.f);
    *reinterpret_cast<float4*>(&out[base + t * 4]) = v;
  }
}

// -------- fused GCN layer (d=128): agg = gather(H); v = relu(agg@W) + H --------
// Gather: wave w (of 4) owns cols [32w,32w+32); lane l owns node n0+l.
// acc in 32 VGPRs, 8 independent dwordx4 loads per edge, next-src prefetch.
// mode 0: out[n] = v. mode 1: G[gid[n]] += v (pool fused).
__global__ __launch_bounds__(256) void k_gcn_fused(
    const float* __restrict__ H, const int* __restrict__ csr,
    const int* __restrict__ offs, const int* __restrict__ cnts,
    const float* __restrict__ W, float* __restrict__ out,
    float* G, const int* __restrict__ gid, int N, int mode) {
  __shared__ float sa[64 * 132];
  int n0 = blockIdx.x * 64;

  // gather phase
  {
    int w = threadIdx.x >> 6;  // column block
    int l = threadIdx.x & 63;  // node lane
    int n = n0 + l;
    float4 acc[8];
#pragma unroll
    for (int q = 0; q < 8; ++q) acc[q] = make_float4(0.f, 0.f, 0.f, 0.f);
    int cnt = (n < N) ? cnts[n] : 0;
    int s = (n < N) ? offs[n] : 0;
    const float* Hw = H + w * 32;
    int src = (cnt > 0) ? csr[s] : 0;
    for (int e = 0; e < cnt; ++e) {
      int nsrc = (e + 1 < cnt) ? csr[s + e + 1] : 0;
      const float4* row = reinterpret_cast<const float4*>(Hw + (size_t)src * 128);
      float4 v0 = row[0], v1 = row[1], v2 = row[2], v3 = row[3];
      float4 v4 = row[4], v5 = row[5], v6 = row[6], v7 = row[7];
      acc[0].x += v0.x; acc[0].y += v0.y; acc[0].z += v0.z; acc[0].w += v0.w;
      acc[1].x += v1.x; acc[1].y += v1.y; acc[1].z += v1.z; acc[1].w += v1.w;
      acc[2].x += v2.x; acc[2].y += v2.y; acc[2].z += v2.z; acc[2].w += v2.w;
      acc[3].x += v3.x; acc[3].y += v3.y; acc[3].z += v3.z; acc[3].w += v3.w;
      acc[4].x += v4.x; acc[4].y += v4.y; acc[4].z += v4.z; acc[4].w += v4.w;
      acc[5].x += v5.x; acc[5].y += v5.y; acc[5].z += v5.z; acc[5].w += v5.w;
      acc[6].x += v6.x; acc[6].y += v6.y; acc[6].z += v6.z; acc[6].w += v6.w;
      acc[7].x += v7.x; acc[7].y += v7.y; acc[7].z += v7.z; acc[7].w += v7.w;
      src = nsrc;
    }
    float* srow = &sa[l * 132 + w * 32];
#pragma unroll
    for (int q = 0; q < 8; ++q)
      *reinterpret_cast<float4*>(srow + q * 4) = acc[q];
  }
  __syncthreads();

  // GEMM 64x128 @ 128x128
  int nl = threadIdx.x >> 4;
  int j0 = (threadIdx.x & 15) * 8;
  float acc[4][8];
#pragma unroll
  for (int r = 0; r < 4; ++r)
#pragma unroll
    for (int j = 0; j < 8; ++j) acc[r][j] = 0.f;
  const float* Wj = W + j0;
#pragma unroll 2
  for (int k = 0; k < 128; ++k) {
    float4 w0 = *reinterpret_cast<const float4*>(Wj + (size_t)k * 128);
    float4 w1 = *reinterpret_cast<const float4*>(Wj + (size_t)k * 128 + 4);
    float wv[8] = {w0.x, w0.y, w0.z, w0.w, w1.x, w1.y, w1.z, w1.w};
#pragma unroll
    for (int r = 0; r < 4; ++r) {
      float a = sa[(nl + 16 * r) * 132 + k];
#pragma unroll
      for (int j = 0; j < 8; ++j) acc[r][j] = fmaf(a, wv[j], acc[r][j]);
    }
  }

  if (mode == 0) {
#pragma unroll
    for (int r = 0; r < 4; ++r) {
      int row = nl + 16 * r;
      int n = n0 + row;
      if (n < N) {
        size_t base = (size_t)n * 128 + j0;
        float4 r0 = *reinterpret_cast<const float4*>(&H[base]);
        float4 r1 = *reinterpret_cast<const float4*>(&H[base + 4]);
        float4 o0, o1;
        o0.x = fmaxf(acc[r][0], 0.f) + r0.x;
        o0.y = fmaxf(acc[r][1], 0.f) + r0.y;
        o0.z = fmaxf(acc[r][2], 0.f) + r0.z;
        o0.w = fmaxf(acc[r][3], 0.f) + r0.w;
        o1.x = fmaxf(acc[r][4], 0.f) + r1.x;
        o1.y = fmaxf(acc[r][5], 0.f) + r1.y;
        o1.z = fmaxf(acc[r][6], 0.f) + r1.z;
        o1.w = fmaxf(acc[r][7], 0.f) + r1.w;
        *reinterpret_cast<float4*>(&out[base]) = o0;
        *reinterpret_cast<float4*>(&out[base + 4]) = o1;
      }
    }
  } else {
    __syncthreads();  // all GEMM reads of sa done
#pragma unroll
    for (int r = 0; r < 4; ++r) {
      int row = nl + 16 * r;
      int n = n0 + row;
      if (n < N) {
        size_t base = (size_t)n * 128 + j0;
        float4 r0 = *reinterpret_cast<const float4*>(&H[base]);
        float4 r1 = *reinterpret_cast<const float4*>(&H[base + 4]);
        float* srow = &sa[row * 132 + j0];
        srow[0] = fmaxf(acc[r][0], 0.f) + r0.x;
        srow[1] = fmaxf(acc[r][1], 0.f) + r0.y;
        srow[2] = fmaxf(acc[r][2], 0.f) + r0.z;
        srow[3] = fmaxf(acc[r][3], 0.f) + r0.w;
        srow[4] = fmaxf(acc[r][4], 0.f) + r1.x;
        srow[5] = fmaxf(acc[r][5], 0.f) + r1.y;
        srow[6] = fmaxf(acc[r][6], 0.f) + r1.z;
        srow[7] = fmaxf(acc[r][7], 0.f) + r1.w;
      }
    }
    __syncthreads();
    int grp = threadIdx.x >> 7;  // 0..1 -> rows [0,32) / [32,64)
    int j = threadIdx.x & 127;
    int r0 = grp * 32;
    int nfirst = n0 + r0;
    if (nfirst < N) {
      float pacc = 0.f;
      int cur = gid[nfirst];
      for (int r = r0; r < r0 + 32; ++r) {
        int n = n0 + r;
        if (n >= N) break;
        int g2 = gid[n];
        if (g2 != cur) {
          atomicAdd(&G[(size_t)cur * 128 + j], pacc);
          pacc = 0.f;
          cur = g2;
        }
        pacc += sa[r * 132 + j];
      }
      atomicAdd(&G[(size_t)cur * 128 + j], pacc);
    }
  }
}

// ---------------- pred = relu(g @ W_p1) @ W_p2 + b ----------------
__global__ __launch_bounds__(64) void k_head(const float* __restrict__ g,
                                             const float* __restrict__ W1,
                                             const float* __restrict__ W2,
                                             const float* __restrict__ b,
                                             float* __restrict__ out) {
  int gi = blockIdx.x;
  int j = threadIdx.x;
  __shared__ float sg[128];
  sg[j] = g[(size_t)gi * 128 + j];
  sg[j + 64] = g[(size_t)gi * 128 + 64 + j];
  __syncthreads();
  float acc = 0.f;
#pragma unroll
  for (int k = 0; k < 128; ++k) acc = fmaf(sg[k], W1[k * 64 + j], acc);
  acc = fmaxf(acc, 0.f) * W2[j];
#pragma unroll
  for (int off = 32; off > 0; off >>= 1) acc += __shfl_down(acc, off);
  if (j == 0) out[gi] = acc + b[0];
}

extern "C" void kernel_launch(void* const* d_in, const int* in_sizes, int n_in,
                              void* d_out, int out_size, void* d_ws, size_t ws_size,
                              hipStream_t stream) {
  const float* x    = (const float*)d_in[0];
  const float* Wemb = (const float*)d_in[1];
  const float* Wg0  = (const float*)d_in[2];
  const float* Wg1  = (const float*)d_in[3];
  const float* Wg2  = (const float*)d_in[4];
  const float* Wp1  = (const float*)d_in[5];
  const float* Wp2  = (const float*)d_in[6];
  const float* bp2  = (const float*)d_in[7];
  const int* esrc   = (const int*)d_in[8];
  const int* edst   = (const int*)d_in[9];
  const int* gids   = (const int*)d_in[10];
  int N = in_sizes[0] / 35;
  int E = in_sizes[8];
  float* out = (float*)d_out;

  // workspace layout
  float* h0 = (float*)d_ws;             // N*8
  float* P  = h0 + (size_t)N * 8;       // N*128
  float* Q  = P + (size_t)N * 128;      // N*128
  float* G  = Q + (size_t)N * 128;      // 2048*128
  int* counts   = (int*)(G + (size_t)NUM_GRAPHS * 128);  // N
  int* offs     = counts + N;                            // N
  int* cursor   = offs + N;                              // N
  int* partials = cursor + N;                            // 512
  int* csr      = partials + 512;                        // E

  int nbE = (E + 255) / 256;
  int nbN = (N + 255) / 256;

  // embed (independent)
  k_embed<<<(N + 31) / 32, 256, 0, stream>>>(x, Wemb, h0, N);

  // CSR build
  hipMemsetAsync(counts, 0, (size_t)N * sizeof(int), stream);
  k_hist<<<nbE, 256, 0, stream>>>(edst, counts, E);
  k_scan1<<<nbN, 256, 0, stream>>>(counts, offs, partials, N);
  k_scan2<<<1, 512, 0, stream>>>(partials, nbN);
  k_scan3<<<nbN, 256, 0, stream>>>(offs, partials, cursor, N);
  k_fill<<<nbE, 256, 0, stream>>>(esrc, edst, cursor, csr, E);

  // zero pooled output (layer-2 epilogue atomics accumulate into it)
  hipMemsetAsync(G, 0, (size_t)NUM_GRAPHS * 128 * sizeof(float), stream);

  // layer 0: P = relu(gather(h0) @ W_g0)
  k_layer0<<<(N + 31) / 32, 256, 0, stream>>>(h0, csr, offs, counts, Wg0, P, N);

  // layer 1: Q = relu(gather(P) @ W_g1) + P
  k_gcn_fused<<<(N + 63) / 64, 256, 0, stream>>>(P, csr, offs, counts, Wg1, Q,
                                                 nullptr, nullptr, N, 0);

  // layer 2 + pool: G[gid] += relu(gather(Q) @ W_g2) + Q
  k_gcn_fused<<<(N + 63) / 64, 256, 0, stream>>>(Q, csr, offs, counts, Wg2, nullptr,
                                                 G, gids, N, 1);

  // head
  k_head<<<NUM_GRAPHS, 64, 0, stream>>>(G, Wp1, Wp2, bp2, out);
}